// Round 2
// baseline (420.995 us; speedup 1.0000x reference)
//
#include <hip/hip_runtime.h>

// GCNConv + ReLU, MI355X. fp32 tensors, edge_index int32.
// out[d] = relu(dn * (h[d]*dn + sum_{e:dst=d} h[src_e]*dis[src_e]) + b),
//   h = x@W (UNSCALED bf16), dis[i] = rsqrt(cnt[i]+1), dn = dis[d].
// R3: CSR + register aggregation (no float atomics)            531us
// R4: [gemm|scatter] fused 1:2 + bf16 h                        398us
// R5 FAILED (735us): multi-change fusion split starved fused kernels.
// R6: aggr 8-deep MLP NEUTRAL; R7: 4-edges-per-gather NEUTRAL  -> aggr is
//     L2/L3 cache-LINE-rate bound (~70us floor), not inst/byte bound.
// R8: delete count+scan chain: stride-64 buckets via atomicAdd.  334us.
// R9: GEMM VALU->MFMA, 3-term bf16 split, pre-swizzled W blob.   327us.
//     fused 148->131.5; VALU 47->8%, Mfma 0->5.7%: GEMM floor gone, but
//     scatter half is latency-bound (1 atomic-return chain per thread,
//     50cy/atomic/CU utilization -> concurrency starvation).
// R10: scatter ILP x8: each thread owns 8 edges, batches 8 loads ->
//     8 independent atomicAdd-returns -> 8 stores. Scatter-first
//     segmented layout (co-resident with gemm). memset+wprep fused.

typedef __attribute__((ext_vector_type(8))) short bf16x8;
typedef __attribute__((ext_vector_type(4))) float f32x4;

__device__ __forceinline__ unsigned short f2bf(float f) {
  unsigned int u = __float_as_uint(f);
  u += 0x7FFFu + ((u >> 16) & 1u);   // RNE
  return (unsigned short)(u >> 16);
}
__device__ __forceinline__ float bfval(unsigned short h) {
  return __uint_as_float(((unsigned int)h) << 16);
}
__device__ __forceinline__ float bf0(unsigned int u) { return __uint_as_float(u << 16); }
__device__ __forceinline__ float bf1(unsigned int u) { return __uint_as_float(u & 0xFFFF0000u); }

// Prologue: W[256][128] -> per-K-chunk(32) LDS images (hi/lo bf16 split,
// XOR bank-swizzle baked in), and zero cnt[N]. One launch.
__global__ __launch_bounds__(256) void k_wprep(
    const float* __restrict__ W, unsigned short* __restrict__ blob,
    unsigned int* __restrict__ cnt, int N)
{
  int g = blockIdx.x * 256 + threadIdx.x;
  if (g < N) cnt[g] = 0u;
  if (g >= 256 * 128) return;
  int k = g >> 7, c = g & 127;
  float w = W[g];
  unsigned short hi = f2bf(w);
  unsigned short lo = f2bf(w - bfval(hi));
  int q = k >> 5, kk = k & 31;
  unsigned lin = (unsigned)(c * 64 + kk * 2);
  unsigned swz = lin ^ (((unsigned)(c & 7)) << 4);
  blob[(q * 16384 + swz) >> 1] = hi;
  blob[(q * 16384 + 8192 + swz) >> 1] = lo;
}

// Fused: bucket scatter (blocks [0,scatB), 2048 edges/block, 8/thread)
// and gemm tiles (h = x@W -> bf16, MFMA) in blocks [scatB, scatB+gemmB).
// GEMM: 256 thr = 4 waves, tile 32 rows x 128 cols, K-chunk 32.
// mfma_f32_16x16x32_bf16: A/B lane l: 8 contig k = 8*(l>>4)+j;
// C/D: col = l&15, row = 4*(l>>4)+reg.
__global__ __launch_bounds__(256) void k_gemm_scatter(
    const float* __restrict__ x, const unsigned char* __restrict__ wblob,
    unsigned short* __restrict__ h, int N,
    const int* __restrict__ src, const int* __restrict__ dst,
    unsigned int* __restrict__ cnt, int* __restrict__ srcs, int E,
    int gemmB, int scatB)
{
  // B images [0,16384), A hi [16384,18432), A lo [18432,20480)
  __shared__ __align__(16) unsigned char smem[20480];

  const int id = blockIdx.x;
  const bool isGemm = id >= scatB;          // scatter blocks dispatch first
  const int tid = threadIdx.x;

  if (!isGemm) {
    const int e0 = id * 2048 + tid;         // 8 edges/thread, stride 256
    int d[8], s[8];
    #pragma unroll
    for (int i = 0; i < 8; ++i) {
      const int e = e0 + i * 256;
      const bool ok = e < E;
      d[i] = ok ? dst[e] : -1;
      s[i] = ok ? src[e] : 0;
    }
    #pragma unroll
    for (int i = 0; i < 8; ++i) {
      if (d[i] >= 0) {
        int pos = (int)atomicAdd(&cnt[d[i]], 1u);
        if (pos < 64) srcs[((size_t)d[i] << 6) + pos] = s[i];
      }
    }
    return;
  }

  const int idx = id - scatB;
  if (idx >= gemmB) return;

  const int row0 = idx * 32;
  const int lane = tid & 63;
  const int wv = tid >> 6;
  const int mb = wv & 1;
  const int nb = wv >> 1;

  f32x4 acc[4] = {};

  // A-staging indices (per thread: one float4 = 4 k of one row)
  const int ar = tid >> 3;
  const int akk0 = (tid & 7) * 4;
  int arow = row0 + ar; if (arow >= N) arow = N - 1;
  const unsigned aaddr = ((unsigned)(ar * 64 + akk0 * 2)) ^ (((unsigned)(ar & 7)) << 4);

  // compute-side offsets
  const int rr = 16 * mb + (lane & 15);
  const unsigned aoff = ((unsigned)(rr * 64 + (lane >> 4) * 16)) ^ (((unsigned)(rr & 7)) << 4);

  for (int q = 0; q < 8; ++q) {
    // ---- stage A: load fp32, split to bf16 hi/lo, swizzled ds_write
    {
      const float4 v = *(const float4*)(x + (size_t)arow * 256 + q * 32 + akk0);
      unsigned short h0 = f2bf(v.x), h1 = f2bf(v.y), h2 = f2bf(v.z), h3 = f2bf(v.w);
      unsigned short l0 = f2bf(v.x - bfval(h0));
      unsigned short l1 = f2bf(v.y - bfval(h1));
      unsigned short l2 = f2bf(v.z - bfval(h2));
      unsigned short l3 = f2bf(v.w - bfval(h3));
      *(uint2*)(smem + 16384 + aaddr) =
          make_uint2((unsigned)h0 | ((unsigned)h1 << 16), (unsigned)h2 | ((unsigned)h3 << 16));
      *(uint2*)(smem + 18432 + aaddr) =
          make_uint2((unsigned)l0 | ((unsigned)l1 << 16), (unsigned)l2 | ((unsigned)l3 << 16));
    }
    // ---- stage B: identity-copy 16KB pre-swizzled image (L2-resident)
    {
      const uint4* gb = (const uint4*)(wblob + (size_t)q * 16384);
      uint4* sb = (uint4*)smem;
      uint4 t0 = gb[tid], t1 = gb[tid + 256], t2 = gb[tid + 512], t3 = gb[tid + 768];
      sb[tid] = t0; sb[tid + 256] = t1; sb[tid + 512] = t2; sb[tid + 768] = t3;
    }
    __syncthreads();
    // ---- MFMA: 4 n-frags x (hh + hl + lh)
    {
      const bf16x8 ah = *(const bf16x8*)(smem + 16384 + aoff);
      const bf16x8 al = *(const bf16x8*)(smem + 18432 + aoff);
      #pragma unroll
      for (int nf = 0; nf < 4; ++nf) {
        const int c = 64 * nb + 16 * nf + (lane & 15);
        const unsigned boff =
            ((unsigned)(c * 64 + (lane >> 4) * 16)) ^ (((unsigned)(c & 7)) << 4);
        const bf16x8 bh = *(const bf16x8*)(smem + boff);
        const bf16x8 bl = *(const bf16x8*)(smem + 8192 + boff);
        acc[nf] = __builtin_amdgcn_mfma_f32_16x16x32_bf16(ah, bh, acc[nf], 0, 0, 0);
        acc[nf] = __builtin_amdgcn_mfma_f32_16x16x32_bf16(ah, bl, acc[nf], 0, 0, 0);
        acc[nf] = __builtin_amdgcn_mfma_f32_16x16x32_bf16(al, bh, acc[nf], 0, 0, 0);
      }
    }
    __syncthreads();
  }

  // ---- epilogue: D frag (col=l&15, row=4*(l>>4)+r) -> bf16 h
  #pragma unroll
  for (int nf = 0; nf < 4; ++nf) {
    const int col = 64 * nb + 16 * nf + (lane & 15);
    #pragma unroll
    for (int r = 0; r < 4; ++r) {
      const int row = row0 + 16 * mb + 4 * (lane >> 4) + r;
      if (row < N) h[(size_t)row * 128 + col] = f2bf(acc[nf][r]);
    }
  }
}

// Aggregation (unchanged R8 structure): one wave64 per dst node.
__global__ __launch_bounds__(256) void k_aggr(
    const unsigned short* __restrict__ h, const int* __restrict__ srcs,
    const unsigned int* __restrict__ cnt,
    const float* __restrict__ b, float* __restrict__ out, int N)
{
  const int wid = (int)(((size_t)blockIdx.x * 256 + threadIdx.x) >> 6);  // node id
  if (wid >= N) return;                       // wave-uniform
  const int lane = threadIdx.x & 63;
  const int eg = lane >> 4;                   // 0..3
  const int cl = lane & 15;                   // 0..15
  const int deg = min((int)cnt[wid], 64);
  const int m = deg + 1;                      // + self
  const size_t coff = (size_t)(cl << 3);      // 8 channels per lane
  const size_t lbase = (size_t)wid << 6;

  float a0 = 0.f, a1 = 0.f, a2 = 0.f, a3 = 0.f, a4 = 0.f, a5 = 0.f, a6 = 0.f, a7 = 0.f;

  for (int base = 0; base < m; base += 64) {
    const int kk = min(64, m - base);
    const int slot = base + lane;
    int sidx = wid;
    if (slot < deg) sidx = srcs[lbase + slot];
    const float sd = rsqrtf((float)(cnt[sidx] + 1u));
    int j = 0;
    for (; j + 8 <= kk; j += 8) {             // 2 gathers in flight, 8 edges
      const int s0 = __shfl(sidx, j + eg, 64);
      const int s1 = __shfl(sidx, j + 4 + eg, 64);
      const float d0 = __shfl(sd, j + eg, 64);
      const float d1 = __shfl(sd, j + 4 + eg, 64);
      const uint4 v0 = *(const uint4*)(h + ((size_t)s0 << 7) + coff);
      const uint4 v1 = *(const uint4*)(h + ((size_t)s1 << 7) + coff);
      a0 = fmaf(bf0(v0.x), d0, a0); a1 = fmaf(bf1(v0.x), d0, a1);
      a2 = fmaf(bf0(v0.y), d0, a2); a3 = fmaf(bf1(v0.y), d0, a3);
      a4 = fmaf(bf0(v0.z), d0, a4); a5 = fmaf(bf1(v0.z), d0, a5);
      a6 = fmaf(bf0(v0.w), d0, a6); a7 = fmaf(bf1(v0.w), d0, a7);
      a0 = fmaf(bf0(v1.x), d1, a0); a1 = fmaf(bf1(v1.x), d1, a1);
      a2 = fmaf(bf0(v1.y), d1, a2); a3 = fmaf(bf1(v1.y), d1, a3);
      a4 = fmaf(bf0(v1.z), d1, a4); a5 = fmaf(bf1(v1.z), d1, a5);
      a6 = fmaf(bf0(v1.w), d1, a6); a7 = fmaf(bf1(v1.w), d1, a7);
    }
    for (; j < kk; j += 4) {                  // masked tail, 1-4 edges
      const int s0 = __shfl(sidx, j + eg, 64);
      const float d0 = __shfl(sd, j + eg, 64);
      if (j + eg < kk) {
        const uint4 v0 = *(const uint4*)(h + ((size_t)s0 << 7) + coff);
        a0 = fmaf(bf0(v0.x), d0, a0); a1 = fmaf(bf1(v0.x), d0, a1);
        a2 = fmaf(bf0(v0.y), d0, a2); a3 = fmaf(bf1(v0.y), d0, a3);
        a4 = fmaf(bf0(v0.z), d0, a4); a5 = fmaf(bf1(v0.z), d0, a5);
        a6 = fmaf(bf0(v0.w), d0, a6); a7 = fmaf(bf1(v0.w), d0, a7);
      }
    }
  }

  // reduce across the 4 edge-groups (lanes cl, cl+16, cl+32, cl+48)
  a0 += __shfl_xor(a0, 16, 64); a0 += __shfl_xor(a0, 32, 64);
  a1 += __shfl_xor(a1, 16, 64); a1 += __shfl_xor(a1, 32, 64);
  a2 += __shfl_xor(a2, 16, 64); a2 += __shfl_xor(a2, 32, 64);
  a3 += __shfl_xor(a3, 16, 64); a3 += __shfl_xor(a3, 32, 64);
  a4 += __shfl_xor(a4, 16, 64); a4 += __shfl_xor(a4, 32, 64);
  a5 += __shfl_xor(a5, 16, 64); a5 += __shfl_xor(a5, 32, 64);
  a6 += __shfl_xor(a6, 16, 64); a6 += __shfl_xor(a6, 32, 64);
  a7 += __shfl_xor(a7, 16, 64); a7 += __shfl_xor(a7, 32, 64);

  if (lane < 32) {
    const float dn = rsqrtf((float)m);
    const int hi = lane >> 4;                 // 0: regs a0..a3, 1: regs a4..a7
    const int c0 = ((lane & 15) << 3) + (hi << 2);
    const float4 bb = *(const float4*)(b + c0);
    const float r0 = hi ? a4 : a0;
    const float r1 = hi ? a5 : a1;
    const float r2 = hi ? a6 : a2;
    const float r3 = hi ? a7 : a3;
    float4 o;
    o.x = fmaxf(fmaf(dn, r0, bb.x), 0.f);
    o.y = fmaxf(fmaf(dn, r1, bb.y), 0.f);
    o.z = fmaxf(fmaf(dn, r2, bb.z), 0.f);
    o.w = fmaxf(fmaf(dn, r3, bb.w), 0.f);
    *(float4*)(out + ((size_t)wid << 7) + c0) = o;
  }
}

extern "C" void kernel_launch(void* const* d_in, const int* in_sizes, int n_in,
                              void* d_out, int out_size, void* d_ws, size_t ws_size,
                              hipStream_t stream)
{
  const float* x  = (const float*)d_in[0];
  const int* ei   = (const int*)d_in[1];
  const float* W  = (const float*)d_in[2];
  const float* b  = (const float*)d_in[3];
  float* out = (float*)d_out;

  const int Cout = in_sizes[3];            // 128
  const int Cin  = in_sizes[2] / Cout;     // 256
  const int N    = in_sizes[0] / Cin;      // 100000
  const int E    = in_sizes[1] / 2;        // 1600000

  const int* src = ei;
  const int* dst = ei + E;

  char* p = (char*)d_ws;
  size_t off = 0;
  auto alloc = [&](size_t bytes) { char* q = p + off; off = (off + bytes + 255) & ~(size_t)255; return q; };
  unsigned int* cnt = (unsigned int*)alloc((size_t)N * 4);
  int* srcs         = (int*)alloc((size_t)N * 64 * 4);              // stride-64 buckets
  unsigned short* h = (unsigned short*)alloc((size_t)N * Cout * 2); // bf16, ~52MB total
  unsigned short* wblob = (unsigned short*)alloc(8 * 16384);        // 128KB LDS images

  const int gemmB = (N + 31) / 32;         // 3125
  const int scatB = (E + 2047) / 2048;     // 782 (8 edges/thread)

  const int prepThreads = (N > 256 * 128) ? N : 256 * 128;
  k_wprep<<<(prepThreads + 255) / 256, 256, 0, stream>>>(W, wblob, cnt, N);
  k_gemm_scatter<<<scatB + gemmB, 256, 0, stream>>>(x, (const unsigned char*)wblob, h, N,
                                                    src, dst, cnt, srcs, E,
                                                    gemmB, scatB);
  k_aggr<<<(N + 3) / 4, 256, 0, stream>>>(h, srcs, cnt, b, out, N);
}

// Round 3
// 321.324 us; speedup vs baseline: 1.3102x; 1.3102x over previous
//
#include <hip/hip_runtime.h>

// GCNConv + ReLU, MI355X. fp32 tensors, edge_index int32.
// out[d] = relu(dn * (h[d]*dn + sum_{e:dst=d} h[src_e]*dis[src_e]) + b),
//   h = x@W (UNSCALED bf16), dis[i] = rsqrt(cnt[i]+1), dn = dis[d].
// R3: CSR + register aggregation (no float atomics)            531us
// R4: [gemm|scatter] fused 1:2 + bf16 h                        398us
// R5 FAILED (735us): split kernels serialize on the stream.
// R6/R7 NEUTRAL -> aggr is cache-LINE-rate bound, not inst bound.
// R8: stride-64 buckets via atomicAdd (no count+scan).          334us
// R9: GEMM VALU->MFMA (3-term bf16 split, pre-swizzled W blob). 327us
//     fused 148->131.5, VALU 47->8%: GEMM floor gone.
// R10 FAILED (421us): 8 edges/thread serialized the atomic->store
//     chains and killed TLP. Scatter needs 1 chain/thread.
// R11: R9 structure + nontemporal scatter/stream traffic. WRITE_SIZE
//     122MB >> 35MB dirty footprint = cross-XCD line ping-pong on
//     srcs (random 4B stores from 8 incoherent L2s) + x stream
//     evictions. nt stores (no fill/ownership) + nt loads for x/src/dst.

typedef __attribute__((ext_vector_type(8))) short bf16x8;
typedef __attribute__((ext_vector_type(4))) float f32x4;

__device__ __forceinline__ unsigned short f2bf(float f) {
  unsigned int u = __float_as_uint(f);
  u += 0x7FFFu + ((u >> 16) & 1u);   // RNE
  return (unsigned short)(u >> 16);
}
__device__ __forceinline__ float bfval(unsigned short h) {
  return __uint_as_float(((unsigned int)h) << 16);
}
__device__ __forceinline__ float bf0(unsigned int u) { return __uint_as_float(u << 16); }
__device__ __forceinline__ float bf1(unsigned int u) { return __uint_as_float(u & 0xFFFF0000u); }

// Prologue: W[256][128] -> per-K-chunk(32) LDS images (hi/lo bf16 split,
// XOR bank-swizzle baked in), and zero cnt[N]. One launch.
__global__ __launch_bounds__(256) void k_wprep(
    const float* __restrict__ W, unsigned short* __restrict__ blob,
    unsigned int* __restrict__ cnt, int N)
{
  int g = blockIdx.x * 256 + threadIdx.x;
  if (g < N) cnt[g] = 0u;
  if (g >= 256 * 128) return;
  int k = g >> 7, c = g & 127;
  float w = W[g];
  unsigned short hi = f2bf(w);
  unsigned short lo = f2bf(w - bfval(hi));
  int q = k >> 5, kk = k & 31;
  unsigned lin = (unsigned)(c * 64 + kk * 2);
  unsigned swz = lin ^ (((unsigned)(c & 7)) << 4);
  blob[(q * 16384 + swz) >> 1] = hi;
  blob[(q * 16384 + 8192 + swz) >> 1] = lo;
}

// Fused: gemm tiles (h = x@W -> bf16, MFMA) and bucket scatter, 1:2.
// GEMM: 256 thr = 4 waves, tile 32 rows x 128 cols, K-chunk 32.
// mfma_f32_16x16x32_bf16: A/B lane l: 8 contig k = 8*(l>>4)+j;
// C/D: col = l&15, row = 4*(l>>4)+reg.
__global__ __launch_bounds__(256) void k_gemm_scatter(
    const float* __restrict__ x, const unsigned char* __restrict__ wblob,
    unsigned short* __restrict__ h, int N,
    const int* __restrict__ src, const int* __restrict__ dst,
    unsigned int* __restrict__ cnt, int* __restrict__ srcs, int E,
    int gemmB, int scatB)
{
  // B images [0,16384), A hi [16384,18432), A lo [18432,20480)
  __shared__ __align__(16) unsigned char smem[20480];

  const int id = blockIdx.x;
  bool isGemm;
  int idx;
  if (scatB == 2 * gemmB) {            // exact 1:2 interleave (our shape)
    if (id % 3 == 0) { isGemm = true;  idx = id / 3; }
    else             { isGemm = false; idx = id - 1 - id / 3; }
  } else {                              // generic fallback: segmented
    isGemm = id < gemmB;
    idx = isGemm ? id : id - gemmB;
  }

  const int tid = threadIdx.x;

  if (!isGemm) {
    if (idx < scatB) {
      int e = idx * 256 + tid;
      if (e < E) {
        int d = __builtin_nontemporal_load(dst + e);
        int s = __builtin_nontemporal_load(src + e);
        int pos = (int)atomicAdd(&cnt[d], 1u);
        if (pos < 64) __builtin_nontemporal_store(s, srcs + (((size_t)d << 6) + pos));
      }
    }
    return;
  }
  if (idx >= gemmB) return;

  const int row0 = idx * 32;
  const int lane = tid & 63;
  const int wv = tid >> 6;
  const int mb = wv & 1;
  const int nb = wv >> 1;

  f32x4 acc[4] = {};

  // A-staging indices (per thread: one float4 = 4 k of one row)
  const int ar = tid >> 3;
  const int akk0 = (tid & 7) * 4;
  int arow = row0 + ar; if (arow >= N) arow = N - 1;
  const unsigned aaddr = ((unsigned)(ar * 64 + akk0 * 2)) ^ (((unsigned)(ar & 7)) << 4);

  // compute-side offsets
  const int rr = 16 * mb + (lane & 15);
  const unsigned aoff = ((unsigned)(rr * 64 + (lane >> 4) * 16)) ^ (((unsigned)(rr & 7)) << 4);

  for (int q = 0; q < 8; ++q) {
    // ---- stage A: nt-load fp32 x, split to bf16 hi/lo, swizzled ds_write
    {
      const f32x4 v = __builtin_nontemporal_load(
          (const f32x4*)(x + (size_t)arow * 256 + q * 32 + akk0));
      unsigned short h0 = f2bf(v[0]), h1 = f2bf(v[1]), h2 = f2bf(v[2]), h3 = f2bf(v[3]);
      unsigned short l0 = f2bf(v[0] - bfval(h0));
      unsigned short l1 = f2bf(v[1] - bfval(h1));
      unsigned short l2 = f2bf(v[2] - bfval(h2));
      unsigned short l3 = f2bf(v[3] - bfval(h3));
      *(uint2*)(smem + 16384 + aaddr) =
          make_uint2((unsigned)h0 | ((unsigned)h1 << 16), (unsigned)h2 | ((unsigned)h3 << 16));
      *(uint2*)(smem + 18432 + aaddr) =
          make_uint2((unsigned)l0 | ((unsigned)l1 << 16), (unsigned)l2 | ((unsigned)l3 << 16));
    }
    // ---- stage B: identity-copy 16KB pre-swizzled image (L2-resident)
    {
      const uint4* gb = (const uint4*)(wblob + (size_t)q * 16384);
      uint4* sb = (uint4*)smem;
      uint4 t0 = gb[tid], t1 = gb[tid + 256], t2 = gb[tid + 512], t3 = gb[tid + 768];
      sb[tid] = t0; sb[tid + 256] = t1; sb[tid + 512] = t2; sb[tid + 768] = t3;
    }
    __syncthreads();
    // ---- MFMA: 4 n-frags x (hh + hl + lh)
    {
      const bf16x8 ah = *(const bf16x8*)(smem + 16384 + aoff);
      const bf16x8 al = *(const bf16x8*)(smem + 18432 + aoff);
      #pragma unroll
      for (int nf = 0; nf < 4; ++nf) {
        const int c = 64 * nb + 16 * nf + (lane & 15);
        const unsigned boff =
            ((unsigned)(c * 64 + (lane >> 4) * 16)) ^ (((unsigned)(c & 7)) << 4);
        const bf16x8 bh = *(const bf16x8*)(smem + boff);
        const bf16x8 bl = *(const bf16x8*)(smem + 8192 + boff);
        acc[nf] = __builtin_amdgcn_mfma_f32_16x16x32_bf16(ah, bh, acc[nf], 0, 0, 0);
        acc[nf] = __builtin_amdgcn_mfma_f32_16x16x32_bf16(ah, bl, acc[nf], 0, 0, 0);
        acc[nf] = __builtin_amdgcn_mfma_f32_16x16x32_bf16(al, bh, acc[nf], 0, 0, 0);
      }
    }
    __syncthreads();
  }

  // ---- epilogue: D frag (col=l&15, row=4*(l>>4)+r) -> bf16 h
  #pragma unroll
  for (int nf = 0; nf < 4; ++nf) {
    const int col = 64 * nb + 16 * nf + (lane & 15);
    #pragma unroll
    for (int r = 0; r < 4; ++r) {
      const int row = row0 + 16 * mb + 4 * (lane >> 4) + r;
      if (row < N) h[(size_t)row * 128 + col] = f2bf(acc[nf][r]);
    }
  }
}

// Aggregation (unchanged R8 structure): one wave64 per dst node.
__global__ __launch_bounds__(256) void k_aggr(
    const unsigned short* __restrict__ h, const int* __restrict__ srcs,
    const unsigned int* __restrict__ cnt,
    const float* __restrict__ b, float* __restrict__ out, int N)
{
  const int wid = (int)(((size_t)blockIdx.x * 256 + threadIdx.x) >> 6);  // node id
  if (wid >= N) return;                       // wave-uniform
  const int lane = threadIdx.x & 63;
  const int eg = lane >> 4;                   // 0..3
  const int cl = lane & 15;                   // 0..15
  const int deg = min((int)cnt[wid], 64);
  const int m = deg + 1;                      // + self
  const size_t coff = (size_t)(cl << 3);      // 8 channels per lane
  const size_t lbase = (size_t)wid << 6;

  float a0 = 0.f, a1 = 0.f, a2 = 0.f, a3 = 0.f, a4 = 0.f, a5 = 0.f, a6 = 0.f, a7 = 0.f;

  for (int base = 0; base < m; base += 64) {
    const int kk = min(64, m - base);
    const int slot = base + lane;
    int sidx = wid;
    if (slot < deg) sidx = srcs[lbase + slot];
    const float sd = rsqrtf((float)(cnt[sidx] + 1u));
    int j = 0;
    for (; j + 8 <= kk; j += 8) {             // 2 gathers in flight, 8 edges
      const int s0 = __shfl(sidx, j + eg, 64);
      const int s1 = __shfl(sidx, j + 4 + eg, 64);
      const float d0 = __shfl(sd, j + eg, 64);
      const float d1 = __shfl(sd, j + 4 + eg, 64);
      const uint4 v0 = *(const uint4*)(h + ((size_t)s0 << 7) + coff);
      const uint4 v1 = *(const uint4*)(h + ((size_t)s1 << 7) + coff);
      a0 = fmaf(bf0(v0.x), d0, a0); a1 = fmaf(bf1(v0.x), d0, a1);
      a2 = fmaf(bf0(v0.y), d0, a2); a3 = fmaf(bf1(v0.y), d0, a3);
      a4 = fmaf(bf0(v0.z), d0, a4); a5 = fmaf(bf1(v0.z), d0, a5);
      a6 = fmaf(bf0(v0.w), d0, a6); a7 = fmaf(bf1(v0.w), d0, a7);
      a0 = fmaf(bf0(v1.x), d1, a0); a1 = fmaf(bf1(v1.x), d1, a1);
      a2 = fmaf(bf0(v1.y), d1, a2); a3 = fmaf(bf1(v1.y), d1, a3);
      a4 = fmaf(bf0(v1.z), d1, a4); a5 = fmaf(bf1(v1.z), d1, a5);
      a6 = fmaf(bf0(v1.w), d1, a6); a7 = fmaf(bf1(v1.w), d1, a7);
    }
    for (; j < kk; j += 4) {                  // masked tail, 1-4 edges
      const int s0 = __shfl(sidx, j + eg, 64);
      const float d0 = __shfl(sd, j + eg, 64);
      if (j + eg < kk) {
        const uint4 v0 = *(const uint4*)(h + ((size_t)s0 << 7) + coff);
        a0 = fmaf(bf0(v0.x), d0, a0); a1 = fmaf(bf1(v0.x), d0, a1);
        a2 = fmaf(bf0(v0.y), d0, a2); a3 = fmaf(bf1(v0.y), d0, a3);
        a4 = fmaf(bf0(v0.z), d0, a4); a5 = fmaf(bf1(v0.z), d0, a5);
        a6 = fmaf(bf0(v0.w), d0, a6); a7 = fmaf(bf1(v0.w), d0, a7);
      }
    }
  }

  // reduce across the 4 edge-groups (lanes cl, cl+16, cl+32, cl+48)
  a0 += __shfl_xor(a0, 16, 64); a0 += __shfl_xor(a0, 32, 64);
  a1 += __shfl_xor(a1, 16, 64); a1 += __shfl_xor(a1, 32, 64);
  a2 += __shfl_xor(a2, 16, 64); a2 += __shfl_xor(a2, 32, 64);
  a3 += __shfl_xor(a3, 16, 64); a3 += __shfl_xor(a3, 32, 64);
  a4 += __shfl_xor(a4, 16, 64); a4 += __shfl_xor(a4, 32, 64);
  a5 += __shfl_xor(a5, 16, 64); a5 += __shfl_xor(a5, 32, 64);
  a6 += __shfl_xor(a6, 16, 64); a6 += __shfl_xor(a6, 32, 64);
  a7 += __shfl_xor(a7, 16, 64); a7 += __shfl_xor(a7, 32, 64);

  if (lane < 32) {
    const float dn = rsqrtf((float)m);
    const int hi = lane >> 4;                 // 0: regs a0..a3, 1: regs a4..a7
    const int c0 = ((lane & 15) << 3) + (hi << 2);
    const float4 bb = *(const float4*)(b + c0);
    const float r0 = hi ? a4 : a0;
    const float r1 = hi ? a5 : a1;
    const float r2 = hi ? a6 : a2;
    const float r3 = hi ? a7 : a3;
    float4 o;
    o.x = fmaxf(fmaf(dn, r0, bb.x), 0.f);
    o.y = fmaxf(fmaf(dn, r1, bb.y), 0.f);
    o.z = fmaxf(fmaf(dn, r2, bb.z), 0.f);
    o.w = fmaxf(fmaf(dn, r3, bb.w), 0.f);
    *(float4*)(out + ((size_t)wid << 7) + c0) = o;
  }
}

extern "C" void kernel_launch(void* const* d_in, const int* in_sizes, int n_in,
                              void* d_out, int out_size, void* d_ws, size_t ws_size,
                              hipStream_t stream)
{
  const float* x  = (const float*)d_in[0];
  const int* ei   = (const int*)d_in[1];
  const float* W  = (const float*)d_in[2];
  const float* b  = (const float*)d_in[3];
  float* out = (float*)d_out;

  const int Cout = in_sizes[3];            // 128
  const int Cin  = in_sizes[2] / Cout;     // 256
  const int N    = in_sizes[0] / Cin;      // 100000
  const int E    = in_sizes[1] / 2;        // 1600000

  const int* src = ei;
  const int* dst = ei + E;

  char* p = (char*)d_ws;
  size_t off = 0;
  auto alloc = [&](size_t bytes) { char* q = p + off; off = (off + bytes + 255) & ~(size_t)255; return q; };
  unsigned int* cnt = (unsigned int*)alloc((size_t)N * 4);
  int* srcs         = (int*)alloc((size_t)N * 64 * 4);              // stride-64 buckets
  unsigned short* h = (unsigned short*)alloc((size_t)N * Cout * 2); // bf16, ~52MB total
  unsigned short* wblob = (unsigned short*)alloc(8 * 16384);        // 128KB LDS images

  const int gemmB = (N + 31) / 32;         // 3125
  const int scatB = (E + 255) / 256;       // 6250 (1 edge/thread)

  const int prepThreads = (N > 256 * 128) ? N : 256 * 128;
  k_wprep<<<(prepThreads + 255) / 256, 256, 0, stream>>>(W, wblob, cnt, N);
  k_gemm_scatter<<<scatB + gemmB, 256, 0, stream>>>(x, (const unsigned char*)wblob, h, N,
                                                    src, dst, cnt, srcs, E,
                                                    gemmB, scatB);
  k_aggr<<<(N + 3) / 4, 256, 0, stream>>>(h, srcs, cnt, b, out, N);
}